// Round 8
// baseline (256.197 us; speedup 1.0000x reference)
//
#include <hip/hip_runtime.h>
#include <hip/hip_bf16.h>

typedef __bf16 bf16_t;
typedef __bf16 bf16x8 __attribute__((ext_vector_type(8)));
typedef float  floatx4 __attribute__((ext_vector_type(4)));

#define BQ 16
#define NTOK 2048
#define DIM 256
#define HD 64

// ---------------- Kernel 0: W -> W^T bf16, + zero out-accumulator & rowsums ----------------
__global__ __launch_bounds__(256) void k_prep(const float* __restrict__ Wq,
                                              const float* __restrict__ Wk,
                                              const float* __restrict__ Wv,
                                              bf16_t* __restrict__ wt,
                                              float* __restrict__ outz,
                                              float* __restrict__ rsz) {
    int o = blockIdx.x * 256 + threadIdx.x;   // grid 1024 -> o < 262144
    if (o < 49152) {
        int w = o >> 14;
        int r = o & 16383;
        int h = r >> 8;
        int d = r & 255;
        const float* W = (w == 0) ? Wq : ((w == 1) ? Wk : Wv);
        wt[o] = (bf16_t)W[d * 64 + h];
    }
    // zero out (524288 float4) + rs (8192 float4)
    float4 z = make_float4(0.f, 0.f, 0.f, 0.f);
    for (int u = o; u < 532480; u += 262144) {
        if (u < 524288) ((float4*)outz)[u] = z;
        else            ((float4*)rsz)[u - 524288] = z;
    }
}

// ---------------- Kernel 1: fused QKV projection (64 tokens/block, 512 blocks) ----------------
#define XS 264
__global__ __launch_bounds__(256) void k_qkv(const float* __restrict__ x,
                                             const bf16_t* __restrict__ wt,
                                             const float* __restrict__ bq,
                                             const float* __restrict__ bk,
                                             const float* __restrict__ bv,
                                             bf16_t* __restrict__ qb,
                                             bf16_t* __restrict__ kb,
                                             bf16_t* __restrict__ vt) {
    __shared__ bf16_t x_ls[64 * XS];    // 33792 B
    __shared__ bf16_t vt_ls[64 * 72];   //  9216 B

    int b  = blockIdx.x >> 5;
    int t0 = (blockIdx.x & 31) << 6;
    int t  = threadIdx.x;
    int lane = t & 63;
    int w    = t >> 6;
    int m_   = lane & 15;
    int q4   = lane >> 4;

    const bf16_t* wrow = wt + (16 * w + m_) * 256 + q4 * 8;

    bf16x8 bfr[2][3];
    #pragma unroll
    for (int wi = 0; wi < 3; ++wi)
        bfr[0][wi] = *(const bf16x8*)(wrow + wi * 16384);

    for (int tau = t; tau < 4096; tau += 256) {
        int row = tau >> 6, ch = tau & 63;
        float4 v = ((const float4*)x)[(size_t)(b * NTOK + t0 + row) * 64 + ch];
        bf16_t tmp[4] = {(bf16_t)v.x, (bf16_t)v.y, (bf16_t)v.z, (bf16_t)v.w};
        *(uint2*)(&x_ls[row * XS + ch * 4]) = *(uint2*)tmp;
    }
    __syncthreads();

    floatx4 acc[3][4];
    #pragma unroll
    for (int wi = 0; wi < 3; ++wi)
        #pragma unroll
        for (int mt = 0; mt < 4; ++mt) acc[wi][mt] = floatx4{0.f, 0.f, 0.f, 0.f};

    #pragma unroll
    for (int ks = 0; ks < 8; ++ks) {
        if (ks < 7) {
            #pragma unroll
            for (int wi = 0; wi < 3; ++wi)
                bfr[(ks + 1) & 1][wi] = *(const bf16x8*)(wrow + wi * 16384 + (ks + 1) * 32);
        }
        #pragma unroll
        for (int mt = 0; mt < 4; ++mt) {
            bf16x8 afrag = *(const bf16x8*)(&x_ls[(16 * mt + m_) * XS + ks * 32 + q4 * 8]);
            #pragma unroll
            for (int wi = 0; wi < 3; ++wi)
                acc[wi][mt] = __builtin_amdgcn_mfma_f32_16x16x32_bf16(afrag, bfr[ks & 1][wi], acc[wi][mt], 0, 0, 0);
        }
    }

    float biasq = bq[16 * w + m_];
    float biask = bk[16 * w + m_];
    float biasv = bv[16 * w + m_];

    // Q scale = H^-0.5 * log2(e): A = QK^T then carries the L2E factor needed by
    // k_attn's exp2-based sigmoid/expm1 (L2E fold, kept from round 7).
    #pragma unroll
    for (int mt = 0; mt < 4; ++mt)
        #pragma unroll
        for (int r = 0; r < 4; ++r) {
            int tok = t0 + 16 * mt + 4 * q4 + r;
            qb[(size_t)(b * NTOK + tok) * 64 + 16 * w + m_] = (bf16_t)((acc[0][mt][r] + biasq) * 0.18033688f);
            kb[(size_t)(b * NTOK + tok) * 64 + 16 * w + m_] = (bf16_t)(acc[1][mt][r] + biask);
            vt_ls[(16 * w + m_) * 72 + 16 * mt + 4 * q4 + r] = (bf16_t)(acc[2][mt][r] + biasv);
        }
    __syncthreads();
    for (int tau = t; tau < 512; tau += 256) {
        int h = tau >> 3, ch = tau & 7;
        uint4 val = *(const uint4*)(&vt_ls[h * 72 + ch * 8]);
        *(uint4*)(vt + (size_t)(b * 64 + h) * NTOK + t0 + ch * 8) = val;
    }
}

// ---------------- Kernel 2: fused attention, 64x64 frame, conv on MFMA pipe ----------------
// Round-8: LDS-PIPE-bound (round-7 accounting: ~51% LDS busy + 12% conflict cycles).
// Fix conflicts via STRIDE, not XOR (round-7's XOR doubled conflicts by breaking the
// m_-indexed reads): row stride 152 B (76 elem, = 6 banks mod 32):
//   - scalar b16 stores (rows 4q4-stepped): q4 bank offsets {0,24,16,8} -> disjoint
//   - b128 reads (rows m_-indexed): 6*m_ mod 32 injective over 0..15 -> all distinct
// Round-7's XOR swizzle + rim store-redirect REVERTED (conflicts 8.3M->19.6M);
// L2E fold KEPT (absmax improved, 1 fewer mul/elem).
#define SP 76
#define RINT 62
#define L2E 1.44269504f

static __device__ __forceinline__ bf16x8 as_bf16x8(uint4 u) {
    union { uint4 a; bf16x8 b; } c; c.a = u; return c.b;
}

// (512,3): pin VGPR budget (~85). Round-1 lesson: 2nd arg acts as blocks/CU here.
__global__ __launch_bounds__(512, 3) void k_attn(const bf16_t* __restrict__ qb,
                                                 const bf16_t* __restrict__ kb,
                                                 const bf16_t* __restrict__ vt,
                                                 const float* __restrict__ conv_w,
                                                 const float* __restrict__ conv_b,
                                                 float* __restrict__ outp,
                                                 float* __restrict__ rsg) {
    __shared__ bf16_t k_ls[64 * SP];       // 9728 B  K [frame col j][ch]
    __shared__ bf16_t v_ls[64 * SP];       // 9728 B  V [h][k]
    __shared__ bf16_t a_bf[64 * SP];       // 9728 B  QK^T tile bf16 (conv MFMA operand)
    __shared__ bf16_t p_raw[64 * SP + 8];  // 9744 B  P; +8 guard elems for col -1 stores
    bf16_t* pv_ls = p_raw + 8;             // total 38928 B -> 3 blocks/CU (reg-capped anyway)

    int b  = blockIdx.z;
    int r0 = blockIdx.x * RINT;
    int cy = blockIdx.y;
    int it_beg = (cy * 34) / 3;            // chunks {11,11,12}
    int it_end = ((cy + 1) * 34) / 3;

    int t = threadIdx.x, lane = t & 63, w = t >> 6;
    int m_ = lane & 15, q4 = lane >> 4;
    int wtj = w & 3;             // col tile 0..3
    int wti = (w >> 2) << 1;     // row tile base {0,2}

    const uint* vt32 = (const uint*)vt + (size_t)b * 64 * 1024;
    const bf16_t* kb_b = kb + (size_t)b * NTOK * 64;

    int krow = t >> 3, kch = t & 7;

    uint4 kreg;
    uint  vreg[4];
    auto load_k = [&](int c0) {
        int g = c0 - 1 + krow;
        uint4 val = make_uint4(0u, 0u, 0u, 0u);
        if (g >= 0 && g < NTOK)
            val = *(const uint4*)(kb_b + (size_t)g * 64 + kch * 8);
        kreg = val;
    };
    auto load_v = [&](int c0) {
        int cb2 = (c0 >> 1) + 4 * kch;     // c0 always even
        #pragma unroll
        for (int j = 0; j < 4; ++j) {
            uint val = 0u;
            if (cb2 + j < 1024) val = vt32[krow * 1024 + cb2 + j];
            vreg[j] = val;
        }
    };

    load_k(it_beg * RINT);
    load_v(it_beg * RINT);

    // ---- banded conv B-fragments (RAW weights; A carries the L2E factor) ----
    int koff = ((wtj & 1) << 3) + ((wtj & 2) * 12);
    bf16x8 bK[3];
    #pragma unroll
    for (int di = 0; di < 3; ++di) {
        bf16_t tmp[8];
        #pragma unroll
        for (int jj = 0; jj < 8; ++jj) {
            int d = koff + q4 * 8 + jj - (16 * wtj + m_) + 1;
            tmp[jj] = (bf16_t)((d >= 0 && d < 3) ? conv_w[3 * di + d] : 0.f);
        }
        bK[di] = *(bf16x8*)tmp;
    }
    // C-init: L2E*conv_b + log2(L2E)  (so exp2(-c) = e^{-conv}/L2E directly)
    float cbv2 = conv_b[0] * L2E + 0.52876637f;

    // Q fragments -> registers (loaded once; already L2E-scaled by k_qkv)
    bf16x8 qreg[2][2];
    #pragma unroll
    for (int p = 0; p < 2; ++p) {
        int g = r0 - 1 + 16 * (wti + p) + m_;
        #pragma unroll
        for (int ks = 0; ks < 2; ++ks) {
            uint4 val = make_uint4(0u, 0u, 0u, 0u);
            if (g >= 0 && g < NTOK)
                val = *(const uint4*)(qb + (size_t)(b * NTOK + g) * 64 + ks * 32 + q4 * 8);
            qreg[p][ks] = as_bf16x8(val);
        }
    }

    // one-time zero init of p_raw (guard + semantic col 63 rely on this)
    for (int u = t; u < 2436; u += 512) ((uint*)p_raw)[u] = 0u;

    // prologue: K[it_beg] -> k_ls; start K[it_beg+1]
    *(uint4*)(&k_ls[krow * SP + kch * 8]) = kreg;
    load_k((it_beg + 1) * RINT);

    floatx4 accO[2], rsacc[2];
    accO[0] = floatx4{0.f, 0.f, 0.f, 0.f};
    accO[1] = floatx4{0.f, 0.f, 0.f, 0.f};
    rsacc[0] = floatx4{0.f, 0.f, 0.f, 0.f};
    rsacc[1] = floatx4{0.f, 0.f, 0.f, 0.f};

    // col mask: frame col j=0 (prev chunk's halo) and j=63 (rim) contribute nothing
    float mj = ((wtj == 0 && m_ == 0) || (wtj == 3 && m_ == 15)) ? 0.f : 1.f;
    int jm1 = 16 * wtj + m_ - 1;           // P column (store target); -1 lands in guard pad

    __syncthreads();

    for (int itg = it_beg; itg < it_end; ++itg) {
        // ---- QK^T: 2 tiles/wave, K=64; D kept fp32 in regs, stored bf16 to a_bf ----
        floatx4 areg[2];
        {
            bf16x8 bfr0 = *(const bf16x8*)(&k_ls[(16 * wtj + m_) * SP + q4 * 8]);
            bf16x8 bfr1 = *(const bf16x8*)(&k_ls[(16 * wtj + m_) * SP + 32 + q4 * 8]);
            #pragma unroll
            for (int p = 0; p < 2; ++p) {
                floatx4 a = floatx4{0.f, 0.f, 0.f, 0.f};
                a = __builtin_amdgcn_mfma_f32_16x16x32_bf16(qreg[p][0], bfr0, a, 0, 0, 0);
                a = __builtin_amdgcn_mfma_f32_16x16x32_bf16(qreg[p][1], bfr1, a, 0, 0, 0);
                areg[p] = a;
                int rbase = 16 * (wti + p) + 4 * q4;
                #pragma unroll
                for (int r = 0; r < 4; ++r)
                    a_bf[(rbase + r) * SP + 16 * wtj + m_] = (bf16_t)a[r];
            }
        }
        __syncthreads();   // B1

        // ---- stage K[itg+1] -> k_ls, V[itg] -> v_ls; then issue next loads ----
        *(uint4*)(&k_ls[krow * SP + kch * 8]) = kreg;
        *(uint4*)(&v_ls[krow * SP + 8 * kch]) = make_uint4(vreg[0], vreg[1], vreg[2], vreg[3]);
        load_k((itg + 2) * RINT);
        load_v((itg + 1) * RINT);

        // ---- conv via 3 chained MFMA per tile + element ops (sig/relu/expm1) ----
        #pragma unroll
        for (int p = 0; p < 2; ++p) {
            int arow = 16 * (wti + p) + m_ - 1;
            floatx4 c = floatx4{cbv2, cbv2, cbv2, cbv2};
            #pragma unroll
            for (int di = 0; di < 3; ++di) {
                int rr = (arow + di) & 63;
                bf16x8 af = *(const bf16x8*)(&a_bf[rr * SP + koff + q4 * 8]);
                c = __builtin_amdgcn_mfma_f32_16x16x32_bf16(af, bK[di], c, 0, 0, 0);
            }
            int rbase = 16 * (wti + p) + 4 * q4;
            #pragma unroll
            for (int r = 0; r < 4; ++r) {
                float e  = __builtin_amdgcn_exp2f(-c[r]);
                float sg = __builtin_amdgcn_rcpf(e + 0.69314718f);   // = L2E*sigmoid(conv)
                float s  = fmaxf(areg[p][r] - sg, 0.f);              // = L2E*relu(a-sig)
                float ev = (__builtin_amdgcn_exp2f(s) - 1.f) * mj;
                if (p == 0 && r == 0) { if (wti == 0) ev = (q4 == 0) ? 0.f : ev; }  // frame row 0
                if (p == 1 && r == 3) { if (wti == 2) ev = (q4 == 3) ? 0.f : ev; }  // frame row 63
                rsacc[p][r] += ev;
                pv_ls[(rbase + r) * SP + jm1] = (bf16_t)ev;
            }
        }
        __syncthreads();   // B2

        // ---- PV: O[64x64] += P @ V, 2 tiles/wave (no barrier after: all next-iter
        //      LDS writes are post-B1[it+1], reached only after every wave's PV) ----
        #pragma unroll
        for (int ks = 0; ks < 2; ++ks) {
            bf16x8 bfr = *(const bf16x8*)(&v_ls[(16 * wtj + m_) * SP + ks * 32 + q4 * 8]);
            #pragma unroll
            for (int p = 0; p < 2; ++p) {
                bf16x8 af = *(const bf16x8*)(&pv_ls[(16 * (wti + p) + m_) * SP + ks * 32 + q4 * 8]);
                accO[p] = __builtin_amdgcn_mfma_f32_16x16x32_bf16(af, bfr, accO[p], 0, 0, 0);
            }
        }
    }

    // ---- epilogue: rowsum (reduce over 16 m_ lanes; 4 col-waves add atomically) ----
    #pragma unroll
    for (int p = 0; p < 2; ++p)
        #pragma unroll
        for (int r = 0; r < 4; ++r) {
            float s = rsacc[p][r];
            s += __shfl_xor(s, 1);
            s += __shfl_xor(s, 2);
            s += __shfl_xor(s, 4);
            s += __shfl_xor(s, 8);
            if (m_ == 0) {
                int grow = r0 + 16 * (wti + p) + 4 * q4 + r - 1;
                if ((unsigned)grow < NTOK) atomicAdd(&rsg[b * NTOK + grow], s);
            }
        }

    // ---- epilogue: partial O -> atomic ----
    #pragma unroll
    for (int p = 0; p < 2; ++p) {
        int rbase = 16 * (wti + p) + 4 * q4;
        #pragma unroll
        for (int r = 0; r < 4; ++r) {
            int i = rbase + r;
            int grow = r0 + i - 1;
            if (i >= 1 && i < 63 && grow < NTOK)
                atomicAdd(&outp[((size_t)(b * NTOK + grow) << 6) + 16 * wtj + m_], accO[p][r]);
        }
    }
}

// ---------------- Kernel 3: normalize out /= (rowsum + eps), in place ----------------
__global__ __launch_bounds__(256) void k_norm(float* __restrict__ out,
                                              const float* __restrict__ rsg) {
    int gid = blockIdx.x * 256 + threadIdx.x;   // 524288 float4s
    float4 o = ((float4*)out)[gid];
    float d = rsg[gid >> 4] + 1e-5f;
    float inv = 1.f / d;
    o.x *= inv; o.y *= inv; o.z *= inv; o.w *= inv;
    ((float4*)out)[gid] = o;
}

extern "C" void kernel_launch(void* const* d_in, const int* in_sizes, int n_in,
                              void* d_out, int out_size, void* d_ws, size_t ws_size,
                              hipStream_t stream) {
    const float* x  = (const float*)d_in[0];
    const float* Wq = (const float*)d_in[1];
    const float* bq = (const float*)d_in[2];
    const float* Wk = (const float*)d_in[3];
    const float* bk = (const float*)d_in[4];
    const float* Wv = (const float*)d_in[5];
    const float* bv = (const float*)d_in[6];
    const float* cw = (const float*)d_in[7];
    const float* cb = (const float*)d_in[8];
    float* out = (float*)d_out;

    char* ws = (char*)d_ws;
    bf16_t* wt = (bf16_t*)ws;                               // 98304 B
    bf16_t* qb = (bf16_t*)(ws + 98304);                     // 4 MB
    bf16_t* kb = (bf16_t*)(ws + 98304 + 4194304);           // 4 MB
    bf16_t* vt = (bf16_t*)(ws + 98304 + 8388608);           // 4 MB
    float*  rsg = (float*)(ws + 98304 + 12582912);          // 128 KB

    k_prep<<<dim3(1024), dim3(256), 0, stream>>>(Wq, Wk, Wv, wt, out, rsg);
    k_qkv<<<dim3(512), dim3(256), 0, stream>>>(x, wt, bq, bk, bv, qb, kb, vt);
    k_attn<<<dim3(34, 3, BQ), dim3(512), 0, stream>>>(qb, kb, vt, cw, cb, out, rsg);
    k_norm<<<dim3(2048), dim3(256), 0, stream>>>(out, rsg);
}

// Round 9
// 198.976 us; speedup vs baseline: 1.2876x; 1.2876x over previous
//
#include <hip/hip_runtime.h>
#include <hip/hip_bf16.h>

typedef __bf16 bf16_t;
typedef __bf16 bf16x8 __attribute__((ext_vector_type(8)));
typedef float  floatx4 __attribute__((ext_vector_type(4)));

#define BQ 16
#define NTOK 2048
#define DIM 256
#define HD 64

// ---------------- Kernel 0: W -> W^T bf16, + zero out-accumulator & rowsums ----------------
__global__ __launch_bounds__(256) void k_prep(const float* __restrict__ Wq,
                                              const float* __restrict__ Wk,
                                              const float* __restrict__ Wv,
                                              bf16_t* __restrict__ wt,
                                              float* __restrict__ outz,
                                              float* __restrict__ rsz) {
    int o = blockIdx.x * 256 + threadIdx.x;   // grid 1024 -> o < 262144
    if (o < 49152) {
        int w = o >> 14;
        int r = o & 16383;
        int h = r >> 8;
        int d = r & 255;
        const float* W = (w == 0) ? Wq : ((w == 1) ? Wk : Wv);
        wt[o] = (bf16_t)W[d * 64 + h];
    }
    // zero out (524288 float4) + rs (8192 float4)
    float4 z = make_float4(0.f, 0.f, 0.f, 0.f);
    for (int u = o; u < 532480; u += 262144) {
        if (u < 524288) ((float4*)outz)[u] = z;
        else            ((float4*)rsz)[u - 524288] = z;
    }
}

// ---------------- Kernel 1: QKV projection (64 tokens/block, 512 blocks) ----------------
#define XS 264
__global__ __launch_bounds__(256) void k_qkv(const float* __restrict__ x,
                                             const bf16_t* __restrict__ wt,
                                             const float* __restrict__ bq,
                                             const float* __restrict__ bk,
                                             const float* __restrict__ bv,
                                             bf16_t* __restrict__ qb,
                                             bf16_t* __restrict__ kb,
                                             bf16_t* __restrict__ vt) {
    __shared__ bf16_t x_ls[64 * XS];
    __shared__ bf16_t vt_ls[64 * 72];

    int b  = blockIdx.x >> 5;
    int t0 = (blockIdx.x & 31) << 6;
    int t  = threadIdx.x;
    int lane = t & 63;
    int w    = t >> 6;
    int m_   = lane & 15;
    int q4   = lane >> 4;

    for (int tau = t; tau < 4096; tau += 256) {
        int row = tau >> 6, ch = tau & 63;
        float4 v = ((const float4*)x)[(size_t)(b * NTOK + t0 + row) * 64 + ch];
        bf16_t tmp[4] = {(bf16_t)v.x, (bf16_t)v.y, (bf16_t)v.z, (bf16_t)v.w};
        *(uint2*)(&x_ls[row * XS + ch * 4]) = *(uint2*)tmp;
    }
    __syncthreads();

    for (int wi = 0; wi < 3; ++wi) {
        const bf16_t* wtw = wt + wi * 16384;
        floatx4 acc[4];
        #pragma unroll
        for (int mt = 0; mt < 4; ++mt) acc[mt] = floatx4{0.f, 0.f, 0.f, 0.f};

        #pragma unroll
        for (int ks = 0; ks < 8; ++ks) {
            bf16x8 bfrag = *(const bf16x8*)(wtw + (16 * w + m_) * 256 + ks * 32 + q4 * 8);
            #pragma unroll
            for (int mt = 0; mt < 4; ++mt) {
                bf16x8 afrag = *(const bf16x8*)(&x_ls[(16 * mt + m_) * XS + ks * 32 + q4 * 8]);
                acc[mt] = __builtin_amdgcn_mfma_f32_16x16x32_bf16(afrag, bfrag, acc[mt], 0, 0, 0);
            }
        }
        const float* bias_p = (wi == 0) ? bq : ((wi == 1) ? bk : bv);
        float bias = bias_p[16 * w + m_];
        // Q scale = H^-0.5 * log2(e): A = QK^T then carries the L2E factor used by
        // k_attn's exp2-based sigmoid/expm1 chain (L2E fold, verified r7/r8).
        float scale = (wi == 0) ? 0.18033688f : 1.0f;

        if (wi < 2) {
            bf16_t* dst = (wi == 0) ? qb : kb;
            #pragma unroll
            for (int mt = 0; mt < 4; ++mt)
                #pragma unroll
                for (int r = 0; r < 4; ++r) {
                    int tok = t0 + 16 * mt + 4 * q4 + r;
                    dst[(size_t)(b * NTOK + tok) * 64 + 16 * w + m_] = (bf16_t)((acc[mt][r] + bias) * scale);
                }
        } else {
            #pragma unroll
            for (int mt = 0; mt < 4; ++mt)
                #pragma unroll
                for (int r = 0; r < 4; ++r)
                    vt_ls[(16 * w + m_) * 72 + 16 * mt + 4 * q4 + r] = (bf16_t)(acc[mt][r] + bias);
            __syncthreads();
            for (int tau = t; tau < 512; tau += 256) {
                int h = tau >> 3, ch = tau & 7;
                uint4 val = *(const uint4*)(&vt_ls[h * 72 + ch * 8]);
                *(uint4*)(vt + (size_t)(b * 64 + h) * NTOK + t0 + ch * 8) = val;
            }
        }
    }
}

// ---------------- Kernel 2: fused attention, 64x64 frame (62x62 interior), 512 threads ----------------
// Round-9: exact restore of the round-2 structure (best measured: k_attn 108.0 us,
// total 201.7) + the L2E fold (r7/r8-verified: raw conv weights, log2(L2E) folded
// into bias, exp2-based chain; absmax improves to ~0.0096).
// Lessons encoded: SP=72 (row stride 144 B: 16B-aligned -> b128 LDS ops stay fused;
// r8's SP=76 broke alignment, +50%); no XOR swizzle (r7: doubled conflicts by
// breaking m_-indexed reads); no launch_bounds min-waves arg (r1: ~30 reg spill).
#define SA 68     // A_ls fp32 stride (cols 64..67 zero pad, 16B-aligned rows)
#define SP 72     // bf16 LDS stride
#define RINT 62
#define L2E 1.44269504f

static __device__ __forceinline__ bf16x8 as_bf16x8(uint4 u) {
    union { uint4 a; bf16x8 b; } c; c.a = u; return c.b;
}

__global__ __launch_bounds__(512) void k_attn(const bf16_t* __restrict__ qb,
                                              const bf16_t* __restrict__ kb,
                                              const bf16_t* __restrict__ vt,
                                              const float* __restrict__ conv_w,
                                              const float* __restrict__ conv_b,
                                              float* __restrict__ outp,
                                              float* __restrict__ rsg) {
    __shared__ bf16_t k_ls[64 * SP];   // 9216 B  [frame col j][ch]
    __shared__ bf16_t v_ls[64 * SP];   // 9216 B  [h][k]; cols 62/63 loaded but P=0 there
    __shared__ bf16_t p_ls[64 * SP];   // 9216 B  [i][k]; rows 0,63 & k>=62 zero
    __shared__ float  A_ls[64 * SA];   // 17408 B -> total 45056 B

    int b  = blockIdx.z;
    int r0 = blockIdx.x * RINT;
    int it_beg = (int)(blockIdx.y * 34) >> 2;         // chunks {8,9,8,9} iters
    int it_end = (int)((blockIdx.y + 1) * 34) >> 2;

    int t = threadIdx.x, lane = t & 63, w = t >> 6;
    int m_ = lane & 15, q4 = lane >> 4;
    int wtj = w & 3;             // col tile 0..3
    int wti = (w >> 2) << 1;     // row tile base {0,2}

    const uint* vt32 = (const uint*)vt + (size_t)b * 64 * 1024;

    uint4 kreg;
    uint  vreg[4];
    // V staging: 2048 uint tasks (64 rows x 32), power-of-2 indexing, no predicates.
    auto prefetch = [&](int c0) {
        {
            int row = t >> 3, ch = t & 7;
            int g = c0 - 1 + row;
            uint4 val = make_uint4(0u, 0u, 0u, 0u);
            if (g >= 0 && g < NTOK)
                val = *(const uint4*)(kb + (size_t)(b * NTOK + g) * 64 + ch * 8);
            kreg = val;
        }
        #pragma unroll
        for (int j = 0; j < 4; ++j) {
            int tau = t + 512 * j;
            int n = c0 + 2 * (tau & 31);
            uint val = 0u;
            if (n < NTOK) val = vt32[(tau >> 5) * 1024 + (n >> 1)];
            vreg[j] = val;
        }
    };

    prefetch(it_beg * RINT);

    // conv weights RAW (A carries the L2E factor via Q pre-scale)
    float cw[9];
    #pragma unroll
    for (int i = 0; i < 9; ++i) cw[i] = conv_w[i];
    // C-init: L2E*conv_b + log2(L2E)  (so exp2(-c) = e^{-conv}/L2E directly)
    float cb = conv_b[0] * L2E + 0.52876637f;

    // Q fragments -> registers (frame rows 16*(wti+p)+m_, loaded once)
    bf16x8 qreg[2][2];
    #pragma unroll
    for (int p = 0; p < 2; ++p) {
        int g = r0 - 1 + 16 * (wti + p) + m_;
        #pragma unroll
        for (int ks = 0; ks < 2; ++ks) {
            uint4 val = make_uint4(0u, 0u, 0u, 0u);
            if (g >= 0 && g < NTOK)
                val = *(const uint4*)(qb + (size_t)(b * NTOK + g) * 64 + ks * 32 + q4 * 8);
            qreg[p][ks] = as_bf16x8(val);
        }
    }

    // one-time zero inits
    for (int u = t; u < 2304; u += 512) ((uint*)p_ls)[u] = 0u;              // whole p_ls
    if (t < 256) A_ls[(t >> 2) * SA + 64 + (t & 3)] = 0.f;                  // A_ls col pad (finite 0 for conv taps)

    floatx4 accO[2];
    accO[0] = floatx4{0.f, 0.f, 0.f, 0.f};
    accO[1] = floatx4{0.f, 0.f, 0.f, 0.f};
    float rs[2] = {0.f, 0.f};

    int i0 = (t >> 4) + 1;     // conv row, round 0 (1..32); round 1 adds 32
    int gq = t & 15;           // quad col group 0..15
    int cvoff = (i0 - 1) * SA + 4 * gq;
    bool gq15 = (gq == 15);    // rim mask: frame col 4*gq+x valid iff <= 61

    for (int itg = it_beg; itg < it_end; ++itg) {
        // ---- regs -> LDS (k_ls, v_ls) ----
        {
            int row = t >> 3, ch = t & 7;
            *(uint4*)(&k_ls[row * SP + ch * 8]) = kreg;
            #pragma unroll
            for (int j = 0; j < 4; ++j) {
                int tau = t + 512 * j;
                *(uint*)(&v_ls[(tau >> 5) * SP + 2 * (tau & 31)]) = vreg[j];
            }
        }
        __syncthreads();

        // ---- QK^T: 16 tiles, 2 per wave, K=64, Q in registers ----
        #pragma unroll
        for (int p = 0; p < 2; ++p) {
            floatx4 a = floatx4{0.f, 0.f, 0.f, 0.f};
            #pragma unroll
            for (int ks = 0; ks < 2; ++ks) {
                bf16x8 bfr = *(const bf16x8*)(&k_ls[(16 * wtj + m_) * SP + ks * 32 + q4 * 8]);
                a = __builtin_amdgcn_mfma_f32_16x16x32_bf16(qreg[p][ks], bfr, a, 0, 0, 0);
            }
            int rbase = 16 * (wti + p) + 4 * q4;
            #pragma unroll
            for (int r = 0; r < 4; ++r)
                A_ls[(rbase + r) * SA + 16 * wtj + m_] = a[r];
        }
        __syncthreads();

        // issue next iter's global loads; latency overlaps conv below
        if (itg + 1 < it_end) prefetch((itg + 1) * RINT);

        // ---- conv + sigmoid + relu + expm1 (1x4 quads, 992 tasks over 2 rounds) ----
        #pragma unroll
        for (int round = 0; round < 2; ++round) {
            if (round == 0 || t < 480) {
                const float* base = &A_ls[cvoff + round * (32 * SA)];
                float a0[6], a1[6], a2[6];
                *(float4*)(a0)     = *(const float4*)(base);
                *(float2*)(a0 + 4) = *(const float2*)(base + 4);
                *(float4*)(a1)     = *(const float4*)(base + SA);
                *(float2*)(a1 + 4) = *(const float2*)(base + SA + 4);
                *(float4*)(a2)     = *(const float4*)(base + 2 * SA);
                *(float2*)(a2 + 4) = *(const float2*)(base + 2 * SA + 4);
                float esum = 0.f;
                bf16_t quad[4];
                #pragma unroll
                for (int x = 0; x < 4; ++x) {
                    float conv = cb
                        + cw[0] * a0[x] + cw[1] * a0[x + 1] + cw[2] * a0[x + 2]
                        + cw[3] * a1[x] + cw[4] * a1[x + 1] + cw[5] * a1[x + 2]
                        + cw[6] * a2[x] + cw[7] * a2[x + 1] + cw[8] * a2[x + 2];
                    float e  = __builtin_amdgcn_exp2f(-conv);
                    float sg = __builtin_amdgcn_rcpf(e + 0.69314718f);   // = L2E*sigmoid
                    float s  = fmaxf(a1[x + 1] - sg, 0.f);               // = L2E*relu(a-sig)
                    float ev = __builtin_amdgcn_exp2f(s) - 1.f;
                    if (x >= 2) ev = gq15 ? 0.f : ev;     // frame cols 62,63 (rim) -> 0
                    quad[x] = (bf16_t)ev;
                    esum += ev;
                }
                rs[round] += esum;
                *(uint2*)(&p_ls[(i0 + round * 32) * SP + 4 * gq]) = *(uint2*)quad;
            }
        }
        __syncthreads();

        // ---- PV: O[64x64] += P @ V, 2 tiles per wave ----
        #pragma unroll
        for (int ks = 0; ks < 2; ++ks) {
            bf16x8 bfr = *(const bf16x8*)(&v_ls[(16 * wtj + m_) * SP + ks * 32 + q4 * 8]);
            #pragma unroll
            for (int p = 0; p < 2; ++p) {
                bf16x8 af = *(const bf16x8*)(&p_ls[(16 * (wti + p) + m_) * SP + ks * 32 + q4 * 8]);
                accO[p] = __builtin_amdgcn_mfma_f32_16x16x32_bf16(af, bfr, accO[p], 0, 0, 0);
            }
        }
        __syncthreads();
    }

    // ---- epilogue: rowsum via 16-lane shfl reduce -> atomic ----
    float s0 = rs[0], s1 = rs[1];
    #pragma unroll
    for (int d = 1; d < 16; d <<= 1) {
        s0 += __shfl_xor(s0, d);
        s1 += __shfl_xor(s1, d);
    }
    if ((t & 15) == 0) {
        int g0 = r0 + i0 - 1;
        if (g0 < NTOK) atomicAdd(&rsg[b * NTOK + g0], s0);
        if (t < 480 && g0 + 32 < NTOK) atomicAdd(&rsg[b * NTOK + g0 + 32], s1);
    }

    // ---- epilogue: partial O -> atomic ----
    #pragma unroll
    for (int p = 0; p < 2; ++p) {
        int rbase = 16 * (wti + p) + 4 * q4;
        #pragma unroll
        for (int r = 0; r < 4; ++r) {
            int i = rbase + r;
            int grow = r0 + i - 1;
            if (i >= 1 && i < 63 && grow < NTOK)
                atomicAdd(&outp[((size_t)(b * NTOK + grow) << 6) + 16 * wtj + m_], accO[p][r]);
        }
    }
}

// ---------------- Kernel 3: normalize out /= (rowsum + eps), in place ----------------
__global__ __launch_bounds__(256) void k_norm(float* __restrict__ out,
                                              const float* __restrict__ rsg) {
    int gid = blockIdx.x * 256 + threadIdx.x;   // 524288 float4s
    float4 o = ((float4*)out)[gid];
    float d = rsg[gid >> 4] + 1e-5f;
    float inv = 1.f / d;
    o.x *= inv; o.y *= inv; o.z *= inv; o.w *= inv;
    ((float4*)out)[gid] = o;
}

extern "C" void kernel_launch(void* const* d_in, const int* in_sizes, int n_in,
                              void* d_out, int out_size, void* d_ws, size_t ws_size,
                              hipStream_t stream) {
    const float* x  = (const float*)d_in[0];
    const float* Wq = (const float*)d_in[1];
    const float* bq = (const float*)d_in[2];
    const float* Wk = (const float*)d_in[3];
    const float* bk = (const float*)d_in[4];
    const float* Wv = (const float*)d_in[5];
    const float* bv = (const float*)d_in[6];
    const float* cw = (const float*)d_in[7];
    const float* cb = (const float*)d_in[8];
    float* out = (float*)d_out;

    char* ws = (char*)d_ws;
    bf16_t* wt = (bf16_t*)ws;                               // 98304 B
    bf16_t* qb = (bf16_t*)(ws + 98304);                     // 4 MB
    bf16_t* kb = (bf16_t*)(ws + 98304 + 4194304);           // 4 MB
    bf16_t* vt = (bf16_t*)(ws + 98304 + 8388608);           // 4 MB
    float*  rsg = (float*)(ws + 98304 + 12582912);          // 128 KB

    k_prep<<<dim3(1024), dim3(256), 0, stream>>>(Wq, Wk, Wv, wt, out, rsg);
    k_qkv<<<dim3(512), dim3(256), 0, stream>>>(x, wt, bq, bk, bv, qb, kb, vt);
    k_attn<<<dim3(34, 4, BQ), dim3(512), 0, stream>>>(qb, kb, vt, cw, cb, out, rsg);
    k_norm<<<dim3(2048), dim3(256), 0, stream>>>(out, rsg);
}